// Round 3
// baseline (82616.614 us; speedup 1.0000x reference)
//
#include <hip/hip_runtime.h>

#define BB 128      // batch
#define TT 1024     // seq len
#define II 64       // input size
#define HH 512      // hidden
#define KK 576      // II + HH
#define NBLK 256    // one block per pair of h-columns
#define NTHR 256

// Persistent LSTM with custom 2-level grid barrier.
// Round-2 lesson: static LDS must stay <= 64KB or the cooperative launch is
// rejected (runtime occupancy check) -> silent zero output. This version:
// single-buffered vx (60.4KB total LDS), register prefetch retained.
__global__ __launch_bounds__(NTHR, 1)
void lstm_persist(const float* __restrict__ x,
                  const float* __restrict__ W_ih,
                  const float* __restrict__ W_hh,
                  const float* __restrict__ b_ih,
                  const float* __restrict__ b_hh,
                  const float* __restrict__ W_fc,
                  const float* __restrict__ b_fc,
                  float* __restrict__ out,
                  float* __restrict__ hbuf,     // 2 x [128][512] f32
                  unsigned* __restrict__ bar)   // 8 group ctrs (128B apart) + master
{
    __shared__ float Wl[8][KK];      // 18432B  rows: gate*2 + jj
    __shared__ float vx[BB][68];     // 34816B  one 64-wide K chunk, pad 68
    __shared__ float gl[8][BB];      //  4096B
    __shared__ float yl[2][BB];      //  1024B
    __shared__ float wfc[HH];        //  2048B
    __shared__ float bias[8];        //    32B   => 60448B total (< 64KB)

    const int u  = threadIdx.x;
    const int g  = blockIdx.x;
    const int j0 = g << 1;

    unsigned epoch = 0;
    unsigned* __restrict__ subc   = bar + ((g & 7) << 5);
    unsigned* __restrict__ master = bar + 256;

    // ---- one-time weight staging ----
    for (int r = 0; r < 8; ++r) {
        const int R = (r >> 1) * HH + j0 + (r & 1);
        for (int k = u; k < KK; k += NTHR)
            Wl[r][k] = (k < II) ? W_ih[(size_t)R * II + k]
                                : W_hh[(size_t)R * HH + (k - II)];
    }
    if (u < 8) {
        const int R = (u >> 1) * HH + j0 + (u & 1);
        bias[u] = b_ih[R] + b_hh[R];
    }
    for (int k = u; k < HH; k += NTHR) wfc[k] = W_fc[k];
    if (u < BB) {   // zero this block's slice of h buffer 0
        hbuf[(size_t)u * HH + j0]     = 0.f;
        hbuf[(size_t)u * HH + j0 + 1] = 0.f;
    }

    const float bfc = b_fc[0];
    const bool  doy = (g == 0);
    const int   bA  = u & 63, bB2 = bA + 64;
    const int   rp  = u >> 6;
    const int   rA  = rp << 1, rB = rA + 1;
    const int   ub  = u & 127, ujj = u >> 7;
    float creg = 0.f;
    float4 rx[8];

#define BAR_ARRIVE() do { __threadfence(); __syncthreads();                        \
    if (u == 0) {                                                                  \
        unsigned old = __hip_atomic_fetch_add(subc, 1u, __ATOMIC_ACQ_REL,          \
                                              __HIP_MEMORY_SCOPE_AGENT);           \
        if ((old & 31u) == 31u)                                                    \
            __hip_atomic_fetch_add(master, 1u, __ATOMIC_RELEASE,                   \
                                   __HIP_MEMORY_SCOPE_AGENT);                      \
    } ++epoch; } while (0)

#define BAR_WAIT() do {                                                            \
    if (u == 0) {                                                                  \
        while (__hip_atomic_load(master, __ATOMIC_RELAXED,                         \
                                 __HIP_MEMORY_SCOPE_AGENT) < (epoch << 3))         \
            __builtin_amdgcn_s_sleep(1);                                           \
    } __syncthreads(); __threadfence(); } while (0)

    // init barrier; prefetch x(t=0) during the wait window
    BAR_ARRIVE();
    #pragma unroll
    for (int r8 = 0; r8 < 8; ++r8) {
        const int flat = u + NTHR * r8, b = flat >> 4, q = flat & 15;
        rx[r8] = *(const float4*)(x + ((size_t)b * TT + 0) * II + (q << 2));
    }
    BAR_WAIT();

    for (int t = 0; t < TT; ++t) {
        const float* __restrict__ hsrc = hbuf + (size_t)(t & 1) * BB * HH;
        float*       __restrict__ hdst = hbuf + (size_t)((t + 1) & 1) * BB * HH;

        float a00 = 0.f, a01 = 0.f, a10 = 0.f, a11 = 0.f;
        float yacc = 0.f;

        for (int ch = 0; ch < 9; ++ch) {
            __syncthreads();   // readers of previous chunk done
            // write prefetched chunk (reg -> LDS)
            #pragma unroll
            for (int r8 = 0; r8 < 8; ++r8) {
                const int flat = u + NTHR * r8, b = flat >> 4, q = flat & 15;
                *(float4*)&vx[b][q << 2] = rx[r8];
            }
            // issue next chunk's global loads (h chunk ch = K cols 64+64*ch)
            if (ch < 8) {
                const int k0 = ch << 6;
                #pragma unroll
                for (int r8 = 0; r8 < 8; ++r8) {
                    const int flat = u + NTHR * r8, b = flat >> 4, q = flat & 15;
                    rx[r8] = *(const float4*)(hsrc + (size_t)b * HH + k0 + (q << 2));
                }
            }
            __syncthreads();   // vx ready

            // gate dots: 2 rows x 2 batch, float4
            {
                const float* __restrict__ wra = &Wl[rA][ch << 6];
                const float* __restrict__ wrb = &Wl[rB][ch << 6];
                const float* __restrict__ va  = &vx[bA][0];
                const float* __restrict__ vb  = &vx[bB2][0];
                #pragma unroll
                for (int k4 = 0; k4 < 16; ++k4) {
                    const float4 wa = *(const float4*)(wra + (k4 << 2));
                    const float4 wb = *(const float4*)(wrb + (k4 << 2));
                    const float4 pa = *(const float4*)(va + (k4 << 2));
                    const float4 pb = *(const float4*)(vb + (k4 << 2));
                    a00 += wa.x*pa.x + wa.y*pa.y + wa.z*pa.z + wa.w*pa.w;
                    a01 += wa.x*pb.x + wa.y*pb.y + wa.z*pb.z + wa.w*pb.w;
                    a10 += wb.x*pa.x + wb.y*pa.y + wb.z*pa.z + wb.w*pa.w;
                    a11 += wb.x*pb.x + wb.y*pb.y + wb.z*pb.z + wb.w*pb.w;
                }
            }
            // y partial from staged h (block 0, one step delayed)
            if (doy && t > 0 && ch > 0) {
                const float* __restrict__ wf = &wfc[((ch - 1) << 6) + (ujj << 5)];
                const float* __restrict__ vv = &vx[ub][ujj << 5];
                #pragma unroll
                for (int k4 = 0; k4 < 8; ++k4) {
                    const float4 f4 = *(const float4*)(wf + (k4 << 2));
                    const float4 v4 = *(const float4*)(vv + (k4 << 2));
                    yacc += f4.x*v4.x + f4.y*v4.y + f4.z*v4.z + f4.w*v4.w;
                }
            }
        }

        if (doy && t > 0) yl[ujj][ub] = yacc;
        gl[rA][bA]  = a00 + bias[rA];
        gl[rA][bB2] = a01 + bias[rA];
        gl[rB][bA]  = a10 + bias[rB];
        gl[rB][bB2] = a11 + bias[rB];
        __syncthreads();

        {   // c/h update: (128 b) x (2 jj)
            const float gi = gl[0 + ujj][ub];
            const float gf = gl[2 + ujj][ub];
            const float gg = gl[4 + ujj][ub];
            const float go = gl[6 + ujj][ub];
            const float si = 1.f / (1.f + expf(-gi));
            const float sf = 1.f / (1.f + expf(-gf));
            const float tg = tanhf(gg);
            const float so = 1.f / (1.f + expf(-go));
            const float c  = sf * creg + si * tg;
            creg = c;
            hdst[(size_t)ub * HH + j0 + ujj] = so * tanhf(c);
            if (doy && t > 0 && u < BB)
                out[(size_t)u * TT + (t - 1)] = yl[0][u] + yl[1][u] + bfc;
        }

        BAR_ARRIVE();
        if (t + 1 < TT) {   // prefetch next x chunk during the spin
            #pragma unroll
            for (int r8 = 0; r8 < 8; ++r8) {
                const int flat = u + NTHR * r8, b = flat >> 4, q = flat & 15;
                rx[r8] = *(const float4*)(x + ((size_t)b * TT + (t + 1)) * II + (q << 2));
            }
        }
        BAR_WAIT();
    }

    // ---- epilogue: y for the last h (block 0 only) ----
    if (doy) {
        const float* __restrict__ hsrc = hbuf + (size_t)(TT & 1) * BB * HH;
        float yacc = 0.f;
        for (int ch = 1; ch < 9; ++ch) {
            const int k0 = (ch - 1) << 6;
            __syncthreads();
            #pragma unroll
            for (int r8 = 0; r8 < 8; ++r8) {
                const int flat = u + NTHR * r8, b = flat >> 4, q = flat & 15;
                *(float4*)&vx[b][q << 2] =
                    *(const float4*)(hsrc + (size_t)b * HH + k0 + (q << 2));
            }
            __syncthreads();
            const float* __restrict__ wf = &wfc[((ch - 1) << 6) + (ujj << 5)];
            const float* __restrict__ vv = &vx[ub][ujj << 5];
            #pragma unroll
            for (int k4 = 0; k4 < 8; ++k4) {
                const float4 f4 = *(const float4*)(wf + (k4 << 2));
                const float4 v4 = *(const float4*)(vv + (k4 << 2));
                yacc += f4.x*v4.x + f4.y*v4.y + f4.z*v4.z + f4.w*v4.w;
            }
        }
        yl[ujj][ub] = yacc;
        __syncthreads();
        if (u < BB) out[(size_t)u * TT + (TT - 1)] = yl[0][u] + yl[1][u] + bfc;
    }
#undef BAR_ARRIVE
#undef BAR_WAIT
}

extern "C" void kernel_launch(void* const* d_in, const int* in_sizes, int n_in,
                              void* d_out, int out_size, void* d_ws, size_t ws_size,
                              hipStream_t stream) {
    (void)in_sizes; (void)n_in; (void)out_size; (void)ws_size;
    const float* x    = (const float*)d_in[0];
    const float* W_ih = (const float*)d_in[1];
    const float* W_hh = (const float*)d_in[2];
    const float* b_ih = (const float*)d_in[3];
    const float* b_hh = (const float*)d_in[4];
    const float* W_fc = (const float*)d_in[5];
    const float* b_fc = (const float*)d_in[6];
    float* out = (float*)d_out;

    unsigned* bar  = (unsigned*)d_ws;                // 257 uints used, 4KB reserved
    float*    hbuf = (float*)((char*)d_ws + 4096);   // 2*128*512*4B = 512KB

    hipMemsetAsync(d_ws, 0, 4096, stream);           // zero barrier counters each call

    void* args[] = {(void*)&x, (void*)&W_ih, (void*)&W_hh, (void*)&b_ih,
                    (void*)&b_hh, (void*)&W_fc, (void*)&b_fc, (void*)&out,
                    (void*)&hbuf, (void*)&bar};
    hipError_t e = hipLaunchCooperativeKernel((const void*)lstm_persist,
                                              dim3(NBLK), dim3(NTHR), args, 0, stream);
    if (e != hipSuccess) {
        // fallback: plain launch (256 small blocks on 256 CUs co-reside)
        hipLaunchKernelGGL(lstm_persist, dim3(NBLK), dim3(NTHR), 0, stream,
                           x, W_ih, W_hh, b_ih, b_hh, W_fc, b_fc, out, hbuf, bar);
    }
}